// Round 9
// baseline (497.566 us; speedup 1.0000x reference)
//
#include <hip/hip_runtime.h>
#include <stdint.h>
#include <stddef.h>

// Problem constants
#define T_SEQ 2048
#define C_DIM 640
#define N_BATCH 8

typedef __bf16 bf16x8 __attribute__((ext_vector_type(8)));
typedef float f32x4 __attribute__((ext_vector_type(4)));

__device__ __forceinline__ unsigned short f2bf(float f) {
  unsigned u = __float_as_uint(f);
  u += 0x7fffu + ((u >> 16) & 1u);   // round-to-nearest-even
  return (unsigned short)(u >> 16);
}
__device__ __forceinline__ float bf2f(unsigned short h) {
  return __uint_as_float(((unsigned)h) << 16);
}

__device__ __forceinline__ void gll16(const unsigned short* src, unsigned short* dst) {
  __builtin_amdgcn_global_load_lds(
      (const __attribute__((address_space(1))) void*)src,
      (__attribute__((address_space(3))) void*)dst, 16, 0, 0);
}

// Stage a 128(rows) x 64(k) bf16 tile into LDS (linear dest, row stride 128B).
// Global source pre-swizzled (rule #21) so swizzled ds_reads (byte ^= (row&7)<<4)
// observe logical data.
__device__ __forceinline__ void stage_tile(const unsigned short* gbase, int ldg,
                                           unsigned short* lbuf, int wave, int lane) {
#pragma unroll
  for (int i = 0; i < 4; ++i) {
    const int o   = i * 4096 + wave * 1024 + lane * 16;  // byte offset in tile
    const int row = o >> 7;
    const int cb  = o & 127;
    const int scb = cb ^ ((row & 7) << 4);               // involution within row
    const unsigned short* src = gbase + (size_t)row * ldg + (scb >> 1);
    unsigned short* dst = lbuf + ((i * 4096 + wave * 1024) >> 1);  // wave-uniform
    gll16(src, dst);
  }
}

// ======================= projection / Mt GEMM (as R8) ========================
// MODE 0: y = xb·Mt^T (bz==0) and V = xb·wv^T stored TRANSPOSED into Vt (bz==1).
// MODE 3: Mt split-K partials: Mpart[bz] = wkT·wqT^T over K-chunk bz (128 wide).
template <int MODE>
__global__ __launch_bounds__(256) void gemm_k(
    const unsigned short* __restrict__ Abase, const unsigned short* __restrict__ Bbase,
    const unsigned short* __restrict__ B2base, unsigned short* __restrict__ OutB,
    unsigned short* __restrict__ OutB2, float* __restrict__ OutF) {
  const int lin = blockIdx.x;
  int mi, ni, bz;
  if constexpr (MODE == 0) {
    // nwg = 1280 = 8 * 160; logical wg = mi*10 + (z*5 + ni)
    const int wg = (lin & 7) * 160 + (lin >> 3);
    mi = wg / 10;
    const int t = wg % 10;
    bz = t / 5;            // z: 0 = y (via Mt), 1 = Vt (via wv)
    ni = t % 5;
  } else {
    // nwg = 125: bz = K-chunk (5 x 128), (mi,ni) in 5x5
    bz = lin / 25;
    const int rem = lin % 25;
    mi = rem / 5;
    ni = rem % 5;
  }

  __shared__ unsigned short As[2][8192];
  __shared__ unsigned short Bs[2][8192];
  const int tid = threadIdx.x;
  const int wave = tid >> 6, lane = tid & 63;
  const int wm = wave >> 1, wn = wave & 1;

  const unsigned short* Ap;
  const unsigned short* Bp;
  int ksteps;
  if constexpr (MODE == 0) {
    Ap = Abase + (size_t)mi * 81920;
    Bp = ((bz == 0) ? Bbase : B2base) + (size_t)ni * 81920;
    ksteps = 10;
  } else {
    Ap = Abase + (size_t)mi * 81920 + bz * 128;
    Bp = Bbase + (size_t)ni * 81920 + bz * 128;
    ksteps = 2;
  }

  f32x4 acc[4][4] = {};
  stage_tile(Ap, 640, As[0], wave, lane);
  stage_tile(Bp, 640, Bs[0], wave, lane);
  __syncthreads();

  int cur = 0;
  for (int t = 0; t < ksteps; ++t) {
    if (t + 1 < ksteps) {
      stage_tile(Ap + (size_t)(t + 1) * 64, 640, As[cur ^ 1], wave, lane);
      stage_tile(Bp + (size_t)(t + 1) * 64, 640, Bs[cur ^ 1], wave, lane);
    }
#pragma unroll
    for (int kk = 0; kk < 2; ++kk) {
      bf16x8 af[4], bfr[4];
#pragma unroll
      for (int mt = 0; mt < 4; ++mt) {
        const int row = wm * 64 + mt * 16 + (lane & 15);
        const int cb  = kk * 64 + ((lane >> 4) << 4);
        af[mt] = *(const bf16x8*)&As[cur][row * 64 + ((cb ^ ((row & 7) << 4)) >> 1)];
      }
#pragma unroll
      for (int nt = 0; nt < 4; ++nt) {
        const int row = wn * 64 + nt * 16 + (lane & 15);
        const int cb  = kk * 64 + ((lane >> 4) << 4);
        bfr[nt] = *(const bf16x8*)&Bs[cur][row * 64 + ((cb ^ ((row & 7) << 4)) >> 1)];
      }
#pragma unroll
      for (int mt = 0; mt < 4; ++mt)
#pragma unroll
        for (int nt = 0; nt < 4; ++nt)
          acc[mt][nt] = __builtin_amdgcn_mfma_f32_16x16x32_bf16(af[mt], bfr[nt],
                                                                acc[mt][nt], 0, 0, 0);
    }
    __syncthreads();
    cur ^= 1;
  }

  // Epilogue. C/D frag: col = lane&15, row = (lane>>4)*4 + r
#pragma unroll
  for (int mt = 0; mt < 4; ++mt) {
#pragma unroll
    for (int nt = 0; nt < 4; ++nt) {
      const int r0 = wm * 64 + mt * 16 + ((lane >> 4) << 2);
      const int c  = wn * 64 + nt * 16 + (lane & 15);
      if constexpr (MODE == 0) {
        if (bz == 0) {  // y, row-major
          const size_t base = (size_t)(mi * 128 + r0) * 640 + ni * 128 + c;
#pragma unroll
          for (int r = 0; r < 4; ++r) OutB[base + (size_t)r * 640] = f2bf(acc[mt][nt][r]);
        } else {        // V, stored transposed into Vt[b][c][t]
          const int b = mi >> 4;
          const int tloc = ((mi & 15) << 7) + r0;  // multiple of 4 -> 8B aligned
          const int gc = ni * 128 + c;
          ushort4 o4;
          o4.x = f2bf(acc[mt][nt][0]); o4.y = f2bf(acc[mt][nt][1]);
          o4.z = f2bf(acc[mt][nt][2]); o4.w = f2bf(acc[mt][nt][3]);
          *(ushort4*)&OutB2[(size_t)b * 1310720 + (size_t)gc * 2048 + tloc] = o4;
        }
      } else {  // MODE 3: fp32 partials
        const size_t base = (size_t)bz * 409600 + (size_t)(mi * 128 + r0) * 640 + ni * 128 + c;
#pragma unroll
        for (int r = 0; r < 4; ++r) OutF[base + (size_t)r * 640] = acc[mt][nt][r];
      }
    }
  }
}

// ================= fused persistent S + PV kernel ===========================
// 512 persistent blocks (2/CU via 64KB LDS) claim units from a global atomic
// queue. Queue order: mi = 15..0; per mi: 8*(mi+1) S units, then 40 PV units.
// S unit (b,mi,ni): P-tile = exp(y_b·xb_b^T) causal + Lpart, then release-fence
// + atomicAdd(done[b*16+mi]). PV unit (b,mi,nc): acquire-spin until
// done == mi+1, sum Lpart -> 1/L, out = P·Vt/L + xb. Deadlock-free: claims are
// globally ordered and S units never wait, so a spinning PV unit's producers
// are always already claimed by resident blocks (no XCD/placement assumption).
// Output is BIT-IDENTICAL to the split-kernel version (same tiles, same op
// order; L summed in same ascending j order as the old rowsum_k).
#define NU 1728
__global__ __launch_bounds__(256) void attn_k(
    const unsigned short* __restrict__ y, const unsigned short* __restrict__ xb,
    const unsigned short* __restrict__ Vt, unsigned short* __restrict__ P,
    float* __restrict__ Lpart, float* __restrict__ out,
    int* __restrict__ qctr, int* __restrict__ done) {
  __shared__ unsigned short As[2][8192];
  __shared__ unsigned short Bs[2][8192];
  __shared__ float Ls[128];
  __shared__ int s_u;
  const int tid = threadIdx.x;
  const int wave = tid >> 6, lane = tid & 63;
  const int wm = wave >> 1, wn = wave & 1;

  for (;;) {
    __syncthreads();                       // LDS reuse + s_u protection
    if (tid == 0) s_u = atomicAdd(qctr, 1);
    __syncthreads();
    const int u = s_u;
    if (u >= NU) break;

    // decode unit
    int rem = u, mi = 0, sub = 0;
    bool isPV = false;
    for (int m = 15; m >= 0; --m) {
      const int a = 8 * (m + 1);
      if (rem < a) { mi = m; sub = rem; isPV = false; break; }
      rem -= a;
      if (rem < 40) { mi = m; sub = rem; isPV = true; break; }
      rem -= 40;
    }

    const unsigned short *Ap, *Bp;
    int ldA, ldB, ksteps, b, nc;
    if (!isPV) {
      b = sub / (mi + 1); nc = sub % (mi + 1);   // nc = S col-tile, <= mi
      Ap = y  + (size_t)b * 1310720 + (size_t)mi * 81920;
      Bp = xb + (size_t)b * 1310720 + (size_t)nc * 81920;
      ldA = 640; ldB = 640; ksteps = 10;
    } else {
      b = sub / 5; nc = sub % 5;                  // nc = out col-tile
      if (tid == 0) {
        while (__hip_atomic_load(&done[b * 16 + mi], __ATOMIC_ACQUIRE,
                                 __HIP_MEMORY_SCOPE_AGENT) < mi + 1)
          __builtin_amdgcn_s_sleep(1);
      }
      __syncthreads();                            // all lanes see fresh P after acquire
      if (tid < 128) {                            // 1/L per row (ascending j = bit-identical)
        const float* p = &Lpart[((size_t)b * 2048 + mi * 128 + tid) * 32];
        float s = 0.f;
        const int jm = 2 * (mi + 1);
        for (int j = 0; j < jm; ++j) s += p[j];
        Ls[tid] = 1.0f / s;
      }
      Ap = P  + (size_t)b * 4194304 + (size_t)mi * 262144;
      Bp = Vt + (size_t)b * 1310720 + (size_t)nc * 262144;
      ldA = 2048; ldB = 2048; ksteps = 2 * (mi + 1);
    }

    f32x4 acc[4][4] = {};
    stage_tile(Ap, ldA, As[0], wave, lane);
    stage_tile(Bp, ldB, Bs[0], wave, lane);
    __syncthreads();

    int cur = 0;
    for (int t = 0; t < ksteps; ++t) {
      if (t + 1 < ksteps) {
        stage_tile(Ap + (size_t)(t + 1) * 64, ldA, As[cur ^ 1], wave, lane);
        stage_tile(Bp + (size_t)(t + 1) * 64, ldB, Bs[cur ^ 1], wave, lane);
      }
#pragma unroll
      for (int kk = 0; kk < 2; ++kk) {
        bf16x8 af[4], bfr[4];
#pragma unroll
        for (int mt = 0; mt < 4; ++mt) {
          const int row = wm * 64 + mt * 16 + (lane & 15);
          const int cb  = kk * 64 + ((lane >> 4) << 4);
          af[mt] = *(const bf16x8*)&As[cur][row * 64 + ((cb ^ ((row & 7) << 4)) >> 1)];
        }
#pragma unroll
        for (int nt = 0; nt < 4; ++nt) {
          const int row = wn * 64 + nt * 16 + (lane & 15);
          const int cb  = kk * 64 + ((lane >> 4) << 4);
          bfr[nt] = *(const bf16x8*)&Bs[cur][row * 64 + ((cb ^ ((row & 7) << 4)) >> 1)];
        }
#pragma unroll
        for (int mt = 0; mt < 4; ++mt)
#pragma unroll
          for (int nt = 0; nt < 4; ++nt)
            acc[mt][nt] = __builtin_amdgcn_mfma_f32_16x16x32_bf16(af[mt], bfr[nt],
                                                                  acc[mt][nt], 0, 0, 0);
      }
      __syncthreads();
      cur ^= 1;
    }

    // Epilogues. C/D frag: col = lane&15, row = (lane>>4)*4 + r
    if (!isPV) {
#pragma unroll
      for (int mt = 0; mt < 4; ++mt) {
        const int r0 = wm * 64 + mt * 16 + ((lane >> 4) << 2);
        const int grow = mi * 128 + r0;
        float rsum[4] = {0.f, 0.f, 0.f, 0.f};
#pragma unroll
        for (int nt = 0; nt < 4; ++nt) {
          const int gc = nc * 128 + wn * 64 + nt * 16 + (lane & 15);
          const size_t base = (size_t)b * 4194304 + (size_t)grow * 2048 + gc;
#pragma unroll
          for (int r = 0; r < 4; ++r) {
            const float e = (gc <= grow + r) ? __expf(acc[mt][nt][r]) : 0.0f;
            P[base + (size_t)r * 2048] = f2bf(e);
            rsum[r] += e;
          }
        }
#pragma unroll
        for (int off = 1; off < 16; off <<= 1) {
#pragma unroll
          for (int r = 0; r < 4; ++r) rsum[r] += __shfl_xor(rsum[r], off);
        }
        if ((lane & 15) == 0) {
#pragma unroll
          for (int r = 0; r < 4; ++r)
            Lpart[((size_t)b * 2048 + grow + r) * 32 + nc * 2 + wn] = rsum[r];
        }
      }
      __threadfence();                 // release: P + Lpart visible device-wide
      __syncthreads();                 // all threads' fences done
      if (tid == 0) atomicAdd(&done[b * 16 + mi], 1);
    } else {
#pragma unroll
      for (int mt = 0; mt < 4; ++mt) {
#pragma unroll
        for (int nt = 0; nt < 4; ++nt) {
          const int r0 = wm * 64 + mt * 16 + ((lane >> 4) << 2);
          const int c  = wn * 64 + nt * 16 + (lane & 15);
          const int grow = mi * 128 + r0;
          const size_t base = (size_t)b * 1310720 + (size_t)grow * 640 + nc * 128 + c;
#pragma unroll
          for (int r = 0; r < 4; ++r) {
            const float rl = Ls[r0 + r];
            out[base + (size_t)r * 640] =
                acc[mt][nt][r] * rl + bf2f(xb[base + (size_t)r * 640]);
          }
        }
      }
    }
  }
}

__global__ void cast_x_k(const float* __restrict__ x, unsigned short* __restrict__ xb, int n4) {
  const int stride = gridDim.x * blockDim.x;
  for (int i = blockIdx.x * blockDim.x + threadIdx.x; i < n4; i += stride) {
    const float4 v = ((const float4*)x)[i];
    ushort4 o;
    o.x = f2bf(v.x); o.y = f2bf(v.y); o.z = f2bf(v.z); o.w = f2bf(v.w);
    ((ushort4*)xb)[i] = o;
  }
}

// z==0: wq -> wqT (transposed, scaled by 1/sqrt(640)); z==1: wk -> wkT
// (transposed); z==2: wv -> wvb (plain cast). All bf16 out.
__global__ void tcast_w(const float* __restrict__ wq, const float* __restrict__ wk,
                        const float* __restrict__ wv, unsigned short* __restrict__ wqT,
                        unsigned short* __restrict__ wkT, unsigned short* __restrict__ wvb) {
  const int z = blockIdx.y;
  const int tx = threadIdx.x, ty = threadIdx.y;
  if (z == 2) {
    const int e = (blockIdx.x * 256 + ty * 32 + tx) * 4;  // 400*256*4 = 409600
    const float4 v = *(const float4*)&wv[e];
    ushort4 o;
    o.x = f2bf(v.x); o.y = f2bf(v.y); o.z = f2bf(v.z); o.w = f2bf(v.w);
    *(ushort4*)&wvb[e] = o;
    return;
  }
  __shared__ float tile[32][33];
  const float* w = (z == 0) ? wq : wk;
  unsigned short* wT = (z == 0) ? wqT : wkT;
  const float s = (z == 0) ? 0.03952847075210474f : 1.0f;  // 1/sqrt(640)
  const int bo = (blockIdx.x / 20) * 32, bc = (blockIdx.x % 20) * 32;
#pragma unroll
  for (int i = 0; i < 4; ++i)
    tile[ty + i * 8][tx] = w[(size_t)(bo + ty + i * 8) * 640 + bc + tx];
  __syncthreads();
#pragma unroll
  for (int i = 0; i < 4; ++i)
    wT[(size_t)(bc + ty + i * 8) * 640 + bo + tx] = f2bf(tile[tx][ty + i * 8] * s);
}

// Mt[e] = bf16(sum_p Mpart[p][e]), vectorized x4. 400 blocks x 256 threads.
__global__ void reduce_mt(const float* __restrict__ Mpart, unsigned short* __restrict__ Mt) {
  const int e = (blockIdx.x * 256 + threadIdx.x) * 4;
  float4 a = *(const float4*)&Mpart[e];
#pragma unroll
  for (int p = 1; p < 5; ++p) {
    const float4 b = *(const float4*)&Mpart[(size_t)p * 409600 + e];
    a.x += b.x; a.y += b.y; a.z += b.z; a.w += b.w;
  }
  ushort4 o;
  o.x = f2bf(a.x); o.y = f2bf(a.y); o.z = f2bf(a.z); o.w = f2bf(a.w);
  *(ushort4*)&Mt[e] = o;
}

extern "C" void kernel_launch(void* const* d_in, const int* in_sizes, int n_in,
                              void* d_out, int out_size, void* d_ws, size_t ws_size,
                              hipStream_t stream) {
  (void)in_sizes; (void)n_in; (void)out_size; (void)ws_size;
  const float* x  = (const float*)d_in[0];
  const float* wq = (const float*)d_in[1];
  const float* wk = (const float*)d_in[2];
  const float* wv = (const float*)d_in[3];
  float* out = (float*)d_out;

  // Workspace layout (bytes); total 143,655,936 (< 174,489,600 proven-safe)
  char* ws = (char*)d_ws;
  unsigned short* xb  = (unsigned short*)(ws + 0);         // 16384x640 bf16 (live to end)
  unsigned short* wqT = (unsigned short*)(ws + 20971520);  // 640x640 bf16, scaled
  unsigned short* wkT = (unsigned short*)(ws + 21790720);  // 640x640 bf16
  unsigned short* wvb = (unsigned short*)(ws + 22609920);  // 640x640 bf16
  unsigned short* Mt  = (unsigned short*)(ws + 23429120);  // 640x640 bf16 = Wk^T Wq /sqrtC
  unsigned short* y   = (unsigned short*)(ws + 24248320);  // 16384x640 bf16
  unsigned short* Vt  = (unsigned short*)(ws + 45219840);  // 8x640x2048 bf16
  float*          Mpart = (float*)(ws + 66191360);         // 5x640x640 fp32
  float*          Lpart = (float*)(ws + 74383360);         // 16384x32 fp32
  unsigned short* Sb  = (unsigned short*)(ws + 76546048);  // 8x2048x2048 bf16 (P)
  int*            ctrs = (int*)(ws + 143654912);           // qctr + done[128]

  hipMemsetAsync(ctrs, 0, 1024, stream);
  cast_x_k<<<2048, 256, 0, stream>>>(x, xb, 2621440);
  tcast_w<<<dim3(400, 3), dim3(32, 8), 0, stream>>>(wq, wk, wv, wqT, wkT, wvb);
  // Mt partials: 125 blocks (split-K), fp32, then reduce to bf16
  gemm_k<3><<<125, 256, 0, stream>>>(wkT, wqT, nullptr, nullptr, nullptr, Mpart);
  reduce_mt<<<400, 256, 0, stream>>>(Mpart, Mt);
  // y = xb Mt^T and Vt (V fused-transposed): 1280 blocks, XCD-swizzled
  gemm_k<0><<<1280, 256, 0, stream>>>(xb, Mt, wvb, y, Vt, nullptr);
  // Fused persistent S+PV: 512 blocks, fine-grained row-panel deps
  attn_k<<<512, 256, 0, stream>>>(y, xb, Vt, Sb, Lpart, out, ctrs, ctrs + 1);
}

// Round 10
// 155.754 us; speedup vs baseline: 3.1946x; 3.1946x over previous
//
#include <hip/hip_runtime.h>
#include <stdint.h>
#include <stddef.h>

// Problem constants
#define T_SEQ 2048
#define C_DIM 640
#define N_BATCH 8

typedef __bf16 bf16x8 __attribute__((ext_vector_type(8)));
typedef float f32x4 __attribute__((ext_vector_type(4)));

__device__ __forceinline__ unsigned short f2bf(float f) {
  unsigned u = __float_as_uint(f);
  u += 0x7fffu + ((u >> 16) & 1u);   // round-to-nearest-even
  return (unsigned short)(u >> 16);
}
__device__ __forceinline__ float bf2f(unsigned short h) {
  return __uint_as_float(((unsigned)h) << 16);
}

__device__ __forceinline__ void gll16(const unsigned short* src, unsigned short* dst) {
  __builtin_amdgcn_global_load_lds(
      (const __attribute__((address_space(1))) void*)src,
      (__attribute__((address_space(3))) void*)dst, 16, 0, 0);
}

// Stage a 128(rows) x 32(k) bf16 tile (8 KB) into LDS. BK=32 -> 64 B rows, so
// the bank-spread involution is o ^= ((o>>7)&7)<<4 (bits 4-6, per-1KB stripe;
// o>>7 invariant under the XOR). Global source pre-swizzled (rule #21); LDS
// dest linear wave-uniform base (HW adds lane*16). ds_read uses same XOR ->
// even 8-lanes-per-bank-group (the b128 structural minimum, no extra conflict).
__device__ __forceinline__ void stage_tile32(const unsigned short* gbase, int ldg,
                                             unsigned short* lbuf, int wave, int lane) {
#pragma unroll
  for (int i = 0; i < 2; ++i) {
    const int o = i * 4096 + wave * 1024 + lane * 16;  // byte offset in 8 KB tile
    const int a = o ^ (((o >> 7) & 7) << 4);           // involution
    const int row = a >> 6;
    const int colb = a & 63;
    gll16(gbase + (size_t)row * ldg + (colb >> 1),
          lbuf + ((i * 4096 + wave * 1024) >> 1));     // wave-uniform dst
  }
}

// Decode t in [0,136) -> (mi, ni) with t = mi(mi+1)/2 + ni, ni<=mi.
__device__ __forceinline__ void tri_decode(int t, int& mi, int& ni) {
  int m = (int)((__fsqrt_rn(8.0f * (float)t + 1.0f) - 1.0f) * 0.5f);
  while ((m + 1) * (m + 2) / 2 <= t) ++m;
  while (m * (m + 1) / 2 > t) --m;
  mi = m;
  ni = t - m * (m + 1) / 2;
}

// One GEMM, four uses (all operands "row-major, K-contiguous" i.e. B^T layout):
// MODE 0: y = xb·Mt^T (bz==0) and V = xb·wv^T stored TRANSPOSED into Vt (bz==1).
// MODE 1: S=y·xb^T per batch (causal tiles); epilogue: P=exp(S) masked, bf16,
//         + per-tile row sums Lpart. No max-subtraction (scores ~N(0,1)).
// MODE 2: out = P Vt^T / L + xb. L folded in: prologue sums Lpart (ascending j,
//         bit-identical to old rowsum_k). A=P_b, B=Vt_b, fp32 out.
// MODE 3: Mt split-K partials: Mpart[bz] = wkT·wqT^T over K-chunk bz (128 wide).
//
// 128x128 tile, BK=32, 4 waves (2x2), mfma_f32_16x16x32_bf16, acc 4x4 frags.
// THIS ROUND: BK 64->32 halves LDS to 32 KB (2 buffers x (A 8K + B 8K)) ->
// ~5 blocks/CU AND keeps the depth-1 prefetch. R5 vs R7 A/B showed each
// mechanism alone saturates at ~21% MfmaUtil; this is the combined cell.
// Same gll16 bytes / ds_read bytes / MFMA count & K-order per element ->
// bit-identical output to R8 (absmax must stay exactly 0.03125).
// Linear grid + XCD-chunk swizzle (T1); A-tile sharers adjacent.
template <int MODE>
__global__ __launch_bounds__(256) void gemm_k(
    const unsigned short* __restrict__ Abase, const unsigned short* __restrict__ Bbase,
    const unsigned short* __restrict__ B2base, unsigned short* __restrict__ OutB,
    unsigned short* __restrict__ OutB2, float* __restrict__ OutF,
    const unsigned short* __restrict__ Xres, float* __restrict__ Lpart) {
  const int lin = blockIdx.x;
  int mi, ni, bz;
  if constexpr (MODE == 0) {
    // nwg = 1280 = 8 * 160; logical wg = mi*10 + (z*5 + ni)
    const int wg = (lin & 7) * 160 + (lin >> 3);
    mi = wg / 10;
    const int t = wg % 10;
    bz = t / 5;            // z: 0 = y (via Mt), 1 = Vt (via wv)
    ni = t % 5;
  } else if constexpr (MODE == 1) {
    // nwg = 1088 = 8 * 136; XCD k == batch k
    const int wg = (lin & 7) * 136 + (lin >> 3);
    bz = wg / 136;
    tri_decode(wg % 136, mi, ni);
  } else if constexpr (MODE == 2) {
    // nwg = 640 = 8 * 80; heavy row-blocks (long K) dispatched first
    const int wg = (lin & 7) * 80 + (lin >> 3);
    bz = wg / 80;
    const int t = wg % 80;
    mi = 15 - t / 5;
    ni = t % 5;
  } else {
    // nwg = 125: bz = K-chunk (5 x 128), (mi,ni) in 5x5
    bz = lin / 25;
    const int rem = lin % 25;
    mi = rem / 5;
    ni = rem % 5;
  }

  __shared__ unsigned short As[2][4096];  // 2 x 8 KB
  __shared__ unsigned short Bs[2][4096];
  const int tid = threadIdx.x;
  const int wave = tid >> 6, lane = tid & 63;
  const int wm = wave >> 1, wn = wave & 1;

  const unsigned short* Ap;
  const unsigned short* Bp;
  int ldA, ldB, ksteps;
  if constexpr (MODE == 0) {
    Ap = Abase + (size_t)mi * 81920;
    Bp = ((bz == 0) ? Bbase : B2base) + (size_t)ni * 81920;
    ldA = 640; ldB = 640; ksteps = 20;
  } else if constexpr (MODE == 1) {
    Ap = Abase + (size_t)bz * 1310720 + (size_t)mi * 81920;
    Bp = Bbase + (size_t)bz * 1310720 + (size_t)ni * 81920;
    ldA = 640; ldB = 640; ksteps = 20;
  } else if constexpr (MODE == 2) {
    Ap = Abase + (size_t)bz * 4194304 + (size_t)mi * 262144;
    Bp = Bbase + (size_t)bz * 1310720 + (size_t)ni * 262144;
    ldA = 2048; ldB = 2048; ksteps = 4 * (mi + 1);  // causal K bound
  } else {
    Ap = Abase + (size_t)mi * 81920 + bz * 128;
    Bp = Bbase + (size_t)ni * 81920 + bz * 128;
    ldA = 640; ldB = 640; ksteps = 4;
  }

  // MODE 2 prologue: 1/L per row (ascending j order == old rowsum_k, so the
  // final output is bit-identical to the split-kernel version).
  __shared__ float Ls[(MODE == 2) ? 128 : 1];
  if constexpr (MODE == 2) {
    if (tid < 128) {
      const float* p = &Lpart[((size_t)bz * 2048 + mi * 128 + tid) * 32];
      float s = 0.f;
      const int jm = 2 * (mi + 1);
      for (int j = 0; j < jm; ++j) s += p[j];
      Ls[tid] = 1.0f / s;
    }
  }

  f32x4 acc[4][4] = {};
  stage_tile32(Ap, ldA, As[0], wave, lane);
  stage_tile32(Bp, ldB, Bs[0], wave, lane);
  __syncthreads();

  int cur = 0;
  for (int t = 0; t < ksteps; ++t) {
    if (t + 1 < ksteps) {  // issue next-tile loads BEFORE compute (T3-min)
      stage_tile32(Ap + (size_t)(t + 1) * 32, ldA, As[cur ^ 1], wave, lane);
      stage_tile32(Bp + (size_t)(t + 1) * 32, ldB, Bs[cur ^ 1], wave, lane);
    }
    bf16x8 af[4], bfr[4];
#pragma unroll
    for (int mt = 0; mt < 4; ++mt) {
      const int r = wm * 64 + mt * 16 + (lane & 15);
      const int a = r * 64 + ((lane >> 4) << 4);
      af[mt] = *(const bf16x8*)&As[cur][(a ^ (((a >> 7) & 7) << 4)) >> 1];
    }
#pragma unroll
    for (int nt = 0; nt < 4; ++nt) {
      const int r = wn * 64 + nt * 16 + (lane & 15);
      const int a = r * 64 + ((lane >> 4) << 4);
      bfr[nt] = *(const bf16x8*)&Bs[cur][(a ^ (((a >> 7) & 7) << 4)) >> 1];
    }
#pragma unroll
    for (int mt = 0; mt < 4; ++mt)
#pragma unroll
      for (int nt = 0; nt < 4; ++nt)
        acc[mt][nt] = __builtin_amdgcn_mfma_f32_16x16x32_bf16(af[mt], bfr[nt],
                                                              acc[mt][nt], 0, 0, 0);
    __syncthreads();  // drains vmcnt (staged tile ready) + protects buffer reuse
    cur ^= 1;
  }

  // Epilogue. C/D frag: col = lane&15, row = (lane>>4)*4 + r  [m89/m91-verified]
  if constexpr (MODE == 1) {
    // P = exp(S) with causal mask; per-row partial sums -> Lpart[row][ni*2+wn].
#pragma unroll
    for (int mt = 0; mt < 4; ++mt) {
      const int r0 = wm * 64 + mt * 16 + ((lane >> 4) << 2);
      const int grow = mi * 128 + r0;
      float rsum[4] = {0.f, 0.f, 0.f, 0.f};
#pragma unroll
      for (int nt = 0; nt < 4; ++nt) {
        const int gc = ni * 128 + wn * 64 + nt * 16 + (lane & 15);
        const size_t base = (size_t)bz * 4194304 + (size_t)grow * 2048 + gc;
#pragma unroll
        for (int r = 0; r < 4; ++r) {
          const float e = (gc <= grow + r) ? __expf(acc[mt][nt][r]) : 0.0f;
          OutB[base + (size_t)r * 2048] = f2bf(e);
          rsum[r] += e;
        }
      }
#pragma unroll
      for (int off = 1; off < 16; off <<= 1) {
#pragma unroll
        for (int r = 0; r < 4; ++r) rsum[r] += __shfl_xor(rsum[r], off);
      }
      if ((lane & 15) == 0) {
#pragma unroll
        for (int r = 0; r < 4; ++r)
          Lpart[((size_t)bz * 2048 + grow + r) * 32 + ni * 2 + wn] = rsum[r];
      }
    }
  } else {
#pragma unroll
    for (int mt = 0; mt < 4; ++mt) {
#pragma unroll
      for (int nt = 0; nt < 4; ++nt) {
        const int r0 = wm * 64 + mt * 16 + ((lane >> 4) << 2);
        const int c  = wn * 64 + nt * 16 + (lane & 15);
        if constexpr (MODE == 0) {
          if (bz == 0) {  // y, row-major
            const size_t base = (size_t)(mi * 128 + r0) * 640 + ni * 128 + c;
#pragma unroll
            for (int r = 0; r < 4; ++r) OutB[base + (size_t)r * 640] = f2bf(acc[mt][nt][r]);
          } else {        // V, stored transposed into Vt[b][c][t]
            const int b = mi >> 4;
            const int tloc = ((mi & 15) << 7) + r0;  // multiple of 4 -> 8B aligned
            const int gc = ni * 128 + c;
            ushort4 o4;
            o4.x = f2bf(acc[mt][nt][0]); o4.y = f2bf(acc[mt][nt][1]);
            o4.z = f2bf(acc[mt][nt][2]); o4.w = f2bf(acc[mt][nt][3]);
            *(ushort4*)&OutB2[(size_t)b * 1310720 + (size_t)gc * 2048 + tloc] = o4;
          }
        } else if constexpr (MODE == 2) {
          const int grow = mi * 128 + r0;
          const size_t base = (size_t)bz * 1310720 + (size_t)grow * 640 + ni * 128 + c;
#pragma unroll
          for (int r = 0; r < 4; ++r) {
            OutF[base + (size_t)r * 640] =
                acc[mt][nt][r] * Ls[r0 + r] + bf2f(Xres[base + (size_t)r * 640]);
          }
        } else {  // MODE 3: fp32 partials
          const size_t base = (size_t)bz * 409600 + (size_t)(mi * 128 + r0) * 640 + ni * 128 + c;
#pragma unroll
          for (int r = 0; r < 4; ++r) OutF[base + (size_t)r * 640] = acc[mt][nt][r];
        }
      }
    }
  }
}

__global__ void cast_x_k(const float* __restrict__ x, unsigned short* __restrict__ xb, int n4) {
  const int stride = gridDim.x * blockDim.x;
  for (int i = blockIdx.x * blockDim.x + threadIdx.x; i < n4; i += stride) {
    const float4 v = ((const float4*)x)[i];
    ushort4 o;
    o.x = f2bf(v.x); o.y = f2bf(v.y); o.z = f2bf(v.z); o.w = f2bf(v.w);
    ((ushort4*)xb)[i] = o;
  }
}

// z==0: wq -> wqT (transposed, scaled by 1/sqrt(640)); z==1: wk -> wkT
// (transposed); z==2: wv -> wvb (plain cast). All bf16 out.
__global__ void tcast_w(const float* __restrict__ wq, const float* __restrict__ wk,
                        const float* __restrict__ wv, unsigned short* __restrict__ wqT,
                        unsigned short* __restrict__ wkT, unsigned short* __restrict__ wvb) {
  const int z = blockIdx.y;
  const int tx = threadIdx.x, ty = threadIdx.y;
  if (z == 2) {
    const int e = (blockIdx.x * 256 + ty * 32 + tx) * 4;  // 400*256*4 = 409600
    const float4 v = *(const float4*)&wv[e];
    ushort4 o;
    o.x = f2bf(v.x); o.y = f2bf(v.y); o.z = f2bf(v.z); o.w = f2bf(v.w);
    *(ushort4*)&wvb[e] = o;
    return;
  }
  __shared__ float tile[32][33];
  const float* w = (z == 0) ? wq : wk;
  unsigned short* wT = (z == 0) ? wqT : wkT;
  const float s = (z == 0) ? 0.03952847075210474f : 1.0f;  // 1/sqrt(640)
  const int bo = (blockIdx.x / 20) * 32, bc = (blockIdx.x % 20) * 32;
#pragma unroll
  for (int i = 0; i < 4; ++i)
    tile[ty + i * 8][tx] = w[(size_t)(bo + ty + i * 8) * 640 + bc + tx];
  __syncthreads();
#pragma unroll
  for (int i = 0; i < 4; ++i)
    wT[(size_t)(bc + ty + i * 8) * 640 + bo + tx] = f2bf(tile[tx][ty + i * 8] * s);
}

// Mt[e] = bf16(sum_p Mpart[p][e]), vectorized x4. 400 blocks x 256 threads.
__global__ void reduce_mt(const float* __restrict__ Mpart, unsigned short* __restrict__ Mt) {
  const int e = (blockIdx.x * 256 + threadIdx.x) * 4;
  float4 a = *(const float4*)&Mpart[e];
#pragma unroll
  for (int p = 1; p < 5; ++p) {
    const float4 b = *(const float4*)&Mpart[(size_t)p * 409600 + e];
    a.x += b.x; a.y += b.y; a.z += b.z; a.w += b.w;
  }
  ushort4 o;
  o.x = f2bf(a.x); o.y = f2bf(a.y); o.z = f2bf(a.z); o.w = f2bf(a.w);
  *(ushort4*)&Mt[e] = o;
}

extern "C" void kernel_launch(void* const* d_in, const int* in_sizes, int n_in,
                              void* d_out, int out_size, void* d_ws, size_t ws_size,
                              hipStream_t stream) {
  (void)in_sizes; (void)n_in; (void)out_size; (void)ws_size;
  const float* x  = (const float*)d_in[0];
  const float* wq = (const float*)d_in[1];
  const float* wk = (const float*)d_in[2];
  const float* wv = (const float*)d_in[3];
  float* out = (float*)d_out;

  // Workspace layout (bytes); total 143,654,912 (< 174,489,600 proven-safe)
  char* ws = (char*)d_ws;
  unsigned short* xb  = (unsigned short*)(ws + 0);         // 16384x640 bf16 (live to end)
  unsigned short* wqT = (unsigned short*)(ws + 20971520);  // 640x640 bf16, scaled
  unsigned short* wkT = (unsigned short*)(ws + 21790720);  // 640x640 bf16
  unsigned short* wvb = (unsigned short*)(ws + 22609920);  // 640x640 bf16
  unsigned short* Mt  = (unsigned short*)(ws + 23429120);  // 640x640 bf16 = Wk^T Wq /sqrtC
  unsigned short* y   = (unsigned short*)(ws + 24248320);  // 16384x640 bf16
  unsigned short* Vt  = (unsigned short*)(ws + 45219840);  // 8x640x2048 bf16
  float*          Mpart = (float*)(ws + 66191360);         // 5x640x640 fp32
  float*          Lpart = (float*)(ws + 74383360);         // 16384x32 fp32
  unsigned short* Sb  = (unsigned short*)(ws + 76546048);  // 8x2048x2048 bf16 (P)

  cast_x_k<<<2048, 256, 0, stream>>>(x, xb, 2621440);
  tcast_w<<<dim3(400, 3), dim3(32, 8), 0, stream>>>(wq, wk, wv, wqT, wkT, wvb);
  // Mt partials: 125 blocks (split-K), fp32, then reduce to bf16
  gemm_k<3><<<125, 256, 0, stream>>>(wkT, wqT, nullptr, nullptr, nullptr, Mpart,
                                     nullptr, nullptr);
  reduce_mt<<<400, 256, 0, stream>>>(Mpart, Mt);
  // y = xb Mt^T and Vt (V fused-transposed): 1280 blocks, XCD-swizzled
  gemm_k<0><<<1280, 256, 0, stream>>>(xb, Mt, wvb, y, Vt, nullptr, nullptr, nullptr);
  // P = exp(y xb^T) causal + Lpart: 1088 blocks, batch per XCD
  gemm_k<1><<<1088, 256, 0, stream>>>(y, xb, nullptr, Sb, nullptr, nullptr, nullptr,
                                      Lpart);
  // out = P Vt / L + xb (L folded in prologue): 640 blocks, heavy rows first
  gemm_k<2><<<640, 256, 0, stream>>>(Sb, Vt, nullptr, nullptr, nullptr, out, xb,
                                     Lpart);
}

// Round 11
// 148.957 us; speedup vs baseline: 3.3403x; 1.0456x over previous
//
#include <hip/hip_runtime.h>
#include <stdint.h>
#include <stddef.h>

// Problem constants
#define T_SEQ 2048
#define C_DIM 640
#define N_BATCH 8

typedef __bf16 bf16x8 __attribute__((ext_vector_type(8)));
typedef float f32x4 __attribute__((ext_vector_type(4)));

__device__ __forceinline__ unsigned short f2bf(float f) {
  unsigned u = __float_as_uint(f);
  u += 0x7fffu + ((u >> 16) & 1u);   // round-to-nearest-even
  return (unsigned short)(u >> 16);
}
__device__ __forceinline__ float bf2f(unsigned short h) {
  return __uint_as_float(((unsigned)h) << 16);
}

__device__ __forceinline__ void gll16(const unsigned short* src, unsigned short* dst) {
  __builtin_amdgcn_global_load_lds(
      (const __attribute__((address_space(1))) void*)src,
      (__attribute__((address_space(3))) void*)dst, 16, 0, 0);
}

// Stage a 128(rows) x 64(k) bf16 tile into LDS (linear dest, row stride 128B).
// Global source pre-swizzled (rule #21) so swizzled ds_reads (byte ^= (row&7)<<4)
// observe logical data.  [R2-R8 proven 45-54 µs config: BK=64, double-buffered]
__device__ __forceinline__ void stage_tile(const unsigned short* gbase, int ldg,
                                           unsigned short* lbuf, int wave, int lane) {
#pragma unroll
  for (int i = 0; i < 4; ++i) {
    const int o   = i * 4096 + wave * 1024 + lane * 16;  // byte offset in tile
    const int row = o >> 7;
    const int cb  = o & 127;
    const int scb = cb ^ ((row & 7) << 4);               // involution within row
    const unsigned short* src = gbase + (size_t)row * ldg + (scb >> 1);
    unsigned short* dst = lbuf + ((i * 4096 + wave * 1024) >> 1);  // wave-uniform
    gll16(src, dst);
  }
}

// Decode t in [0,136) -> (mi, ni) with t = mi(mi+1)/2 + ni, ni<=mi.
__device__ __forceinline__ void tri_decode(int t, int& mi, int& ni) {
  int m = (int)((__fsqrt_rn(8.0f * (float)t + 1.0f) - 1.0f) * 0.5f);
  while ((m + 1) * (m + 2) / 2 <= t) ++m;
  while (m * (m + 1) / 2 > t) --m;
  mi = m;
  ni = t - m * (m + 1) / 2;
}

// One GEMM, four uses (all operands "row-major, K-contiguous" i.e. B^T layout):
// MODE 0: y = xb·Mt^T (bz==0) and V = xb·wv^T stored TRANSPOSED into Vt (bz==1).
// MODE 1: S=y·xb^T per batch (causal tiles); epilogue: P=exp(S) masked, bf16,
//         + per-tile row sums Lpart. No max-subtraction (scores ~N(0,1)).
// MODE 2: out = P Vt^T / L + xb. L folded: prologue sums Lpart (ascending j ->
//         bit-identical to the old rowsum_k). A=P_b, B=Vt_b, fp32 out.
// MODE 3: Mt split-K partials: Mpart[bz] = wkT·wqT^T over K-chunk bz (128 wide).
// 128x128 tile, BK=64, 4 waves (2x2), mfma_f32_16x16x32_bf16, acc 4x4 frags.
// R5/R8 proven structure: double-buffered 64KB LDS, stage-next-then-compute,
// one barrier per K-step, 2 blocks/CU. (R6: forcing 5 blocks/CU spills;
// R7: single-buffer no better; R10: BK=32 doubles barrier tax, -17%.)
// Linear grid + XCD-chunk swizzle (T1); A-tile sharers adjacent.
template <int MODE>
__global__ __launch_bounds__(256) void gemm_k(
    const unsigned short* __restrict__ Abase, const unsigned short* __restrict__ Bbase,
    const unsigned short* __restrict__ B2base, unsigned short* __restrict__ OutB,
    unsigned short* __restrict__ OutB2, float* __restrict__ OutF,
    const unsigned short* __restrict__ Xres, float* __restrict__ Lpart) {
  const int lin = blockIdx.x;
  int mi, ni, bz;
  if constexpr (MODE == 0) {
    // nwg = 1280 = 8 * 160; logical wg = mi*10 + (z*5 + ni)
    const int wg = (lin & 7) * 160 + (lin >> 3);
    mi = wg / 10;
    const int t = wg % 10;
    bz = t / 5;            // z: 0 = y (via Mt), 1 = Vt (via wv)
    ni = t % 5;
  } else if constexpr (MODE == 1) {
    // nwg = 1088 = 8 * 136; XCD k == batch k
    const int wg = (lin & 7) * 136 + (lin >> 3);
    bz = wg / 136;
    tri_decode(wg % 136, mi, ni);
  } else if constexpr (MODE == 2) {
    // nwg = 640 = 8 * 80; heavy row-blocks (long K) dispatched first
    const int wg = (lin & 7) * 80 + (lin >> 3);
    bz = wg / 80;
    const int t = wg % 80;
    mi = 15 - t / 5;
    ni = t % 5;
  } else {
    // nwg = 125: bz = K-chunk (5 x 128), (mi,ni) in 5x5
    bz = lin / 25;
    const int rem = lin % 25;
    mi = rem / 5;
    ni = rem % 5;
  }

  __shared__ unsigned short As[2][8192];
  __shared__ unsigned short Bs[2][8192];
  const int tid = threadIdx.x;
  const int wave = tid >> 6, lane = tid & 63;
  const int wm = wave >> 1, wn = wave & 1;

  const unsigned short* Ap;
  const unsigned short* Bp;
  int ldA, ldB, ksteps;
  if constexpr (MODE == 0) {
    Ap = Abase + (size_t)mi * 81920;
    Bp = ((bz == 0) ? Bbase : B2base) + (size_t)ni * 81920;
    ldA = 640; ldB = 640; ksteps = 10;
  } else if constexpr (MODE == 1) {
    Ap = Abase + (size_t)bz * 1310720 + (size_t)mi * 81920;
    Bp = Bbase + (size_t)bz * 1310720 + (size_t)ni * 81920;
    ldA = 640; ldB = 640; ksteps = 10;
  } else if constexpr (MODE == 2) {
    Ap = Abase + (size_t)bz * 4194304 + (size_t)mi * 262144;
    Bp = Bbase + (size_t)bz * 1310720 + (size_t)ni * 262144;
    ldA = 2048; ldB = 2048; ksteps = 2 * (mi + 1);  // causal K bound
  } else {
    Ap = Abase + (size_t)mi * 81920 + bz * 128;
    Bp = Bbase + (size_t)ni * 81920 + bz * 128;
    ldA = 640; ldB = 640; ksteps = 2;
  }

  // MODE 2 prologue: 1/L per row (ascending j == old rowsum_k -> bit-identical).
  __shared__ float Ls[(MODE == 2) ? 128 : 1];
  if constexpr (MODE == 2) {
    if (tid < 128) {
      const float* p = &Lpart[((size_t)bz * 2048 + mi * 128 + tid) * 32];
      float s = 0.f;
      const int jm = 2 * (mi + 1);
      for (int j = 0; j < jm; ++j) s += p[j];
      Ls[tid] = 1.0f / s;
    }
  }

  f32x4 acc[4][4] = {};
  stage_tile(Ap, ldA, As[0], wave, lane);
  stage_tile(Bp, ldB, Bs[0], wave, lane);
  __syncthreads();

  int cur = 0;
  for (int t = 0; t < ksteps; ++t) {
    if (t + 1 < ksteps) {  // issue next-tile loads BEFORE compute (T3-min)
      stage_tile(Ap + (size_t)(t + 1) * 64, ldA, As[cur ^ 1], wave, lane);
      stage_tile(Bp + (size_t)(t + 1) * 64, ldB, Bs[cur ^ 1], wave, lane);
    }
#pragma unroll
    for (int kk = 0; kk < 2; ++kk) {
      bf16x8 af[4], bfr[4];
#pragma unroll
      for (int mt = 0; mt < 4; ++mt) {
        const int row = wm * 64 + mt * 16 + (lane & 15);
        const int cb  = kk * 64 + ((lane >> 4) << 4);
        af[mt] = *(const bf16x8*)&As[cur][row * 64 + ((cb ^ ((row & 7) << 4)) >> 1)];
      }
#pragma unroll
      for (int nt = 0; nt < 4; ++nt) {
        const int row = wn * 64 + nt * 16 + (lane & 15);
        const int cb  = kk * 64 + ((lane >> 4) << 4);
        bfr[nt] = *(const bf16x8*)&Bs[cur][row * 64 + ((cb ^ ((row & 7) << 4)) >> 1)];
      }
#pragma unroll
      for (int mt = 0; mt < 4; ++mt)
#pragma unroll
        for (int nt = 0; nt < 4; ++nt)
          acc[mt][nt] = __builtin_amdgcn_mfma_f32_16x16x32_bf16(af[mt], bfr[nt],
                                                                acc[mt][nt], 0, 0, 0);
    }
    __syncthreads();  // drains vmcnt (staged tile ready) + protects buffer reuse
    cur ^= 1;
  }

  // Epilogue. C/D frag: col = lane&15, row = (lane>>4)*4 + r  [m89/m91-verified]
  if constexpr (MODE == 1) {
    // P = exp(S) with causal mask; per-row partial sums -> Lpart[row][ni*2+wn].
#pragma unroll
    for (int mt = 0; mt < 4; ++mt) {
      const int r0 = wm * 64 + mt * 16 + ((lane >> 4) << 2);
      const int grow = mi * 128 + r0;
      float rsum[4] = {0.f, 0.f, 0.f, 0.f};
#pragma unroll
      for (int nt = 0; nt < 4; ++nt) {
        const int gc = ni * 128 + wn * 64 + nt * 16 + (lane & 15);
        const size_t base = (size_t)bz * 4194304 + (size_t)grow * 2048 + gc;
#pragma unroll
        for (int r = 0; r < 4; ++r) {
          const float e = (gc <= grow + r) ? __expf(acc[mt][nt][r]) : 0.0f;
          OutB[base + (size_t)r * 2048] = f2bf(e);
          rsum[r] += e;
        }
      }
#pragma unroll
      for (int off = 1; off < 16; off <<= 1) {
#pragma unroll
        for (int r = 0; r < 4; ++r) rsum[r] += __shfl_xor(rsum[r], off);
      }
      if ((lane & 15) == 0) {
#pragma unroll
        for (int r = 0; r < 4; ++r)
          Lpart[((size_t)bz * 2048 + grow + r) * 32 + ni * 2 + wn] = rsum[r];
      }
    }
  } else {
#pragma unroll
    for (int mt = 0; mt < 4; ++mt) {
#pragma unroll
      for (int nt = 0; nt < 4; ++nt) {
        const int r0 = wm * 64 + mt * 16 + ((lane >> 4) << 2);
        const int c  = wn * 64 + nt * 16 + (lane & 15);
        if constexpr (MODE == 0) {
          if (bz == 0) {  // y, row-major
            const size_t base = (size_t)(mi * 128 + r0) * 640 + ni * 128 + c;
#pragma unroll
            for (int r = 0; r < 4; ++r) OutB[base + (size_t)r * 640] = f2bf(acc[mt][nt][r]);
          } else {        // V, stored transposed into Vt[b][c][t]
            const int b = mi >> 4;
            const int tloc = ((mi & 15) << 7) + r0;  // multiple of 4 -> 8B aligned
            const int gc = ni * 128 + c;
            ushort4 o4;
            o4.x = f2bf(acc[mt][nt][0]); o4.y = f2bf(acc[mt][nt][1]);
            o4.z = f2bf(acc[mt][nt][2]); o4.w = f2bf(acc[mt][nt][3]);
            *(ushort4*)&OutB2[(size_t)b * 1310720 + (size_t)gc * 2048 + tloc] = o4;
          }
        } else if constexpr (MODE == 2) {
          const int grow = mi * 128 + r0;
          const size_t base = (size_t)bz * 1310720 + (size_t)grow * 640 + ni * 128 + c;
#pragma unroll
          for (int r = 0; r < 4; ++r) {
            OutF[base + (size_t)r * 640] =
                acc[mt][nt][r] * Ls[r0 + r] + bf2f(Xres[base + (size_t)r * 640]);
          }
        } else {  // MODE 3: fp32 partials
          const size_t base = (size_t)bz * 409600 + (size_t)(mi * 128 + r0) * 640 + ni * 128 + c;
#pragma unroll
          for (int r = 0; r < 4; ++r) OutF[base + (size_t)r * 640] = acc[mt][nt][r];
        }
      }
    }
  }
}

// Merged preprocessing (one dispatch): blocks 0..1199 transpose/cast weights
// (z = blk/400: wq->wqT scaled, wk->wkT, wv->wvb plain), blocks 1200..3247
// grid-stride cast x -> xb.
__global__ void prep_k(const float* __restrict__ x, const float* __restrict__ wq,
                       const float* __restrict__ wk, const float* __restrict__ wv,
                       unsigned short* __restrict__ xb, unsigned short* __restrict__ wqT,
                       unsigned short* __restrict__ wkT, unsigned short* __restrict__ wvb) {
  const int tid = threadIdx.x;
  if (blockIdx.x >= 1200) {
    const int i0 = (blockIdx.x - 1200) * 256 + tid;
    for (int i = i0; i < 2621440; i += 2048 * 256) {
      const float4 v = ((const float4*)x)[i];
      ushort4 o;
      o.x = f2bf(v.x); o.y = f2bf(v.y); o.z = f2bf(v.z); o.w = f2bf(v.w);
      ((ushort4*)xb)[i] = o;
    }
    return;
  }
  const int z = blockIdx.x / 400;
  const int bx = blockIdx.x % 400;
  const int tx = tid & 31, ty = tid >> 5;
  if (z == 2) {
    const int e = (bx * 256 + tid) * 4;  // 400*256*4 = 409600
    const float4 v = *(const float4*)&wv[e];
    ushort4 o;
    o.x = f2bf(v.x); o.y = f2bf(v.y); o.z = f2bf(v.z); o.w = f2bf(v.w);
    *(ushort4*)&wvb[e] = o;
    return;
  }
  __shared__ float tile[32][33];
  const float* w = (z == 0) ? wq : wk;
  unsigned short* wT = (z == 0) ? wqT : wkT;
  const float s = (z == 0) ? 0.03952847075210474f : 1.0f;  // 1/sqrt(640)
  const int bo = (bx / 20) * 32, bc = (bx % 20) * 32;
#pragma unroll
  for (int i = 0; i < 4; ++i)
    tile[ty + i * 8][tx] = w[(size_t)(bo + ty + i * 8) * 640 + bc + tx];
  __syncthreads();
#pragma unroll
  for (int i = 0; i < 4; ++i)
    wT[(size_t)(bc + ty + i * 8) * 640 + bo + tx] = f2bf(tile[tx][ty + i * 8] * s);
}

// Mt[e] = bf16(sum_p Mpart[p][e]), vectorized x4. 400 blocks x 256 threads.
__global__ void reduce_mt(const float* __restrict__ Mpart, unsigned short* __restrict__ Mt) {
  const int e = (blockIdx.x * 256 + threadIdx.x) * 4;
  float4 a = *(const float4*)&Mpart[e];
#pragma unroll
  for (int p = 1; p < 5; ++p) {
    const float4 b = *(const float4*)&Mpart[(size_t)p * 409600 + e];
    a.x += b.x; a.y += b.y; a.z += b.z; a.w += b.w;
  }
  ushort4 o;
  o.x = f2bf(a.x); o.y = f2bf(a.y); o.z = f2bf(a.z); o.w = f2bf(a.w);
  *(ushort4*)&Mt[e] = o;
}

extern "C" void kernel_launch(void* const* d_in, const int* in_sizes, int n_in,
                              void* d_out, int out_size, void* d_ws, size_t ws_size,
                              hipStream_t stream) {
  (void)in_sizes; (void)n_in; (void)out_size; (void)ws_size;
  const float* x  = (const float*)d_in[0];
  const float* wq = (const float*)d_in[1];
  const float* wk = (const float*)d_in[2];
  const float* wv = (const float*)d_in[3];
  float* out = (float*)d_out;

  // Workspace layout (bytes); total 143,654,912 (< 174,489,600 proven-safe)
  char* ws = (char*)d_ws;
  unsigned short* xb  = (unsigned short*)(ws + 0);         // 16384x640 bf16 (live to end)
  unsigned short* wqT = (unsigned short*)(ws + 20971520);  // 640x640 bf16, scaled
  unsigned short* wkT = (unsigned short*)(ws + 21790720);  // 640x640 bf16
  unsigned short* wvb = (unsigned short*)(ws + 22609920);  // 640x640 bf16
  unsigned short* Mt  = (unsigned short*)(ws + 23429120);  // 640x640 bf16 = Wk^T Wq /sqrtC
  unsigned short* y   = (unsigned short*)(ws + 24248320);  // 16384x640 bf16
  unsigned short* Vt  = (unsigned short*)(ws + 45219840);  // 8x640x2048 bf16
  float*          Mpart = (float*)(ws + 66191360);         // 5x640x640 fp32
  float*          Lpart = (float*)(ws + 74383360);         // 16384x32 fp32
  unsigned short* Sb  = (unsigned short*)(ws + 76546048);  // 8x2048x2048 bf16 (P)

  // Merged prep: weight transpose/cast + x cast, one dispatch
  prep_k<<<3248, 256, 0, stream>>>(x, wq, wk, wv, xb, wqT, wkT, wvb);
  // Mt partials: 125 blocks (split-K), fp32, then reduce to bf16
  gemm_k<3><<<125, 256, 0, stream>>>(wkT, wqT, nullptr, nullptr, nullptr, Mpart,
                                     nullptr, nullptr);
  reduce_mt<<<400, 256, 0, stream>>>(Mpart, Mt);
  // y = xb Mt^T and Vt (V fused-transposed): 1280 blocks, XCD-swizzled
  gemm_k<0><<<1280, 256, 0, stream>>>(xb, Mt, wvb, y, Vt, nullptr, nullptr, nullptr);
  // P = exp(y xb^T) causal + Lpart: 1088 blocks, batch per XCD
  gemm_k<1><<<1088, 256, 0, stream>>>(y, xb, nullptr, Sb, nullptr, nullptr, nullptr,
                                      Lpart);
  // out = P Vt / L + xb (L folded in prologue): 640 blocks, heavy rows first
  gemm_k<2><<<640, 256, 0, stream>>>(Sb, Vt, nullptr, nullptr, nullptr, out, xb,
                                     Lpart);
}